// Round 8
// baseline (24.317 us; speedup 1.0000x reference)
//
#include <hip/hip_runtime.h>
#include <hip/hip_bf16.h>

// APELoss via moment-corrected histogram, 2 dispatches + 8.2KB in-graph memset.
//
// Single GLOBAL INTEGER histogram (count + 2^26 fixed-point first moment),
// accumulated with device-scope integer atomicAdd from NB=32 hist blocks.
// Integer addition is order-independent -> deterministic across replays.
// K2's per-block merge is then a single 8KB read (R7's 16-segment float2
// merge was ~128KB/block).
//
// K1 (NB hist blocks + F/4 fg-fg blocks):
//   - hist blocks: per-warp LDS sub-histograms (4x, cuts LDS-atomic contention
//     ~4x) of a bg slice, summed at writeout into the global int histogram
//     (skip empty bins) + per-block bg max.
//   - fg-fg blocks: exact F x F part (dist2/rank2/cnt2 per row).
// K2 (EB = F/4 eval blocks): load global int hist (int4), convert to float2
//   LDS, evaluate 4 rows over B_BINS bins with first-order Taylor, fold with
//   fg-fg partials + validity into per-block (sper,sval). Publish agent-scope
//   (sc0 sc1, LLC-direct) stores + s_waitcnt vmcnt(0) + relaxed agent
//   atomicAdd (NO __threadfence -- R4: per-block agent fence = L2 writeback,
//   ~15us); block seeing EB-1 reduces partials in fixed order, writes scalar.
//   (R6: software polling + uncached loads LOSE to a dispatch boundary.)
//
// Math (log2 domain): dl = KC*(c - f), mask dl > -KC else -inf.
//   u = 2^dl, o = 1+u, rr = rcp(o): sigmoid = 1-rr, softplus/ln2 = log2(o)
//   d(sigmoid)/dv = LAMB*(1-rr)*rr ; d(softplus/ln2)/dv = KC*(1-rr)
// valid_i = (bg_max > f_i - 1) || fg_pos_count_i > 0.

#define APE_LAMB 4.0f
#define APE_KC   5.770780163555856f   // LAMB * log2(e)
#define APE_LN2  0.6931471805599453f
#define NINF     (-__builtin_inff())

__device__ __forceinline__ float exp2g(float x) { return __builtin_amdgcn_exp2f(x); }
__device__ __forceinline__ float log2g(float x) { return __builtin_amdgcn_logf(x); }
__device__ __forceinline__ float rcpg(float x)  { return __builtin_amdgcn_rcpf(x); }

constexpr int   B_BINS  = 1024;
constexpr int   NB      = 32;     // hist blocks (merge cost no longer scales with NB)
constexpr int   TPB     = 256;
constexpr float BIN_LO  = -5.12f;
constexpr float BIN_DL  = 0.01f;
constexpr float BIN_INV = 100.0f;
constexpr float M1SCALE = 67108864.0f;              // 2^26 (int32 headroom)
constexpr float M1INV   = 1.4901161193847656e-08f;  // 2^-26
constexpr int   ROWS_E  = 4;      // fg rows per eval block
constexpr int   ROWS_B  = 4;      // fg rows per fg-fg block

#define ST_AGENT(p, v) __hip_atomic_store((p), (v), __ATOMIC_RELAXED, __HIP_MEMORY_SCOPE_AGENT)
#define LD_AGENT(p)    __hip_atomic_load((p), __ATOMIC_RELAXED, __HIP_MEMORY_SCOPE_AGENT)

// ---------------- K1: global int hist + bg max + fg-fg ----------------------
__global__ __launch_bounds__(TPB) void ape_phase1(
    const float* __restrict__ logits, const float* __restrict__ ious,
    int F, int M, int chunkH,
    int* __restrict__ gCnt, int* __restrict__ gM1, float* __restrict__ bmaxA,
    float* __restrict__ dist2, float* __restrict__ rank2, float* __restrict__ cnt2)
{
    const int tid  = threadIdx.x;
    const int lane = tid & 63, wid = tid >> 6;

    if ((int)blockIdx.x < NB) {
        // ---- histogram of one bg slice (per-warp sub-hists) ----
        __shared__ int hc[4][B_BINS];
        __shared__ int hm[4][B_BINS];
        for (int b = tid; b < 4 * B_BINS; b += TPB) {
            hc[b >> 10][b & (B_BINS - 1)] = 0;
            hm[b >> 10][b & (B_BINS - 1)] = 0;
        }
        __syncthreads();

        const float* bg = logits + F;
        const int start = (int)blockIdx.x * chunkH;
        const int end   = min(start + chunkH, M);
        float bmax = NINF;

        for (int j = start + tid * 4; j < end; j += TPB * 4) {
            float v[4];
            if (j + 4 <= end) {
                float4 q = *reinterpret_cast<const float4*>(bg + j);
                v[0] = q.x; v[1] = q.y; v[2] = q.z; v[3] = q.w;
            } else {
#pragma unroll
                for (int k = 0; k < 4; ++k) v[k] = (j + k < end) ? bg[j + k] : NINF;
            }
#pragma unroll
            for (int k = 0; k < 4; ++k) {
                if (j + k >= end) continue;
                float x = v[k];
                bmax = fmaxf(bmax, x);
                int b = (int)((x - BIN_LO) * BIN_INV);
                b = min(max(b, 0), B_BINS - 1);
                float c = fmaf((float)b, BIN_DL, BIN_LO + 0.5f * BIN_DL);
                int q = __float2int_rn((x - c) * M1SCALE);
                atomicAdd(&hc[wid][b], 1);
                atomicAdd(&hm[wid][b], q);
            }
        }
        __syncthreads();
        for (int b = tid; b < B_BINS; b += TPB) {
            int c = hc[0][b] + hc[1][b] + hc[2][b] + hc[3][b];
            if (c) {
                int m = hm[0][b] + hm[1][b] + hm[2][b] + hm[3][b];
                atomicAdd(&gCnt[b], c);   // device-scope int atomics:
                atomicAdd(&gM1[b], m);    // order-independent -> deterministic
            }
        }
        __shared__ float rm[4];
        for (int off = 32; off > 0; off >>= 1) bmax = fmaxf(bmax, __shfl_down(bmax, off));
        if (lane == 0) rm[wid] = bmax;
        __syncthreads();
        if (tid == 0)
            bmaxA[blockIdx.x] = fmaxf(fmaxf(rm[0], rm[1]), fmaxf(rm[2], rm[3]));
    } else {
        // ---- fg-fg exact pairwise ----
        const int i0 = ((int)blockIdx.x - NB) * ROWS_B;
        float fgl[ROWS_B], ioui[ROWS_B];
#pragma unroll
        for (int r = 0; r < ROWS_B; ++r) {
            int i = i0 + r;
            fgl[r]  = (i < F) ? logits[i] * APE_KC : __builtin_inff();
            ioui[r] = (i < F) ? ious[i] : 0.f;
        }
        float dist[ROWS_B], rank[ROWS_B], cnt[ROWS_B];
#pragma unroll
        for (int r = 0; r < ROWS_B; ++r) { dist[r]=0.f; rank[r]=0.f; cnt[r]=0.f; }

        for (int j = tid; j < F; j += TPB) {
            float fjl  = logits[j] * APE_KC;
            float iouj = ious[j];
#pragma unroll
            for (int r = 0; r < ROWS_B; ++r) {
                float dl = fjl - fgl[r];
                bool above = dl > -APE_KC;
                float dm = above ? dl : NINF;
                float u  = exp2g(dm);
                float o  = 1.0f + u;
                float sig = 1.0f - rcpg(o);
                float spl = log2g(o);
                bool pos = iouj < ioui[r];
                rank[r] += sig;
                dist[r] += pos ? spl : 0.f;
                cnt[r]  += (above && pos) ? 1.f : 0.f;
            }
        }
        __shared__ float redf[4][ROWS_B * 3];
#pragma unroll
        for (int r = 0; r < ROWS_B; ++r) {
            float d = dist[r], a = rank[r], c = cnt[r];
            for (int off = 32; off > 0; off >>= 1) {
                d += __shfl_down(d, off);
                a += __shfl_down(a, off);
                c += __shfl_down(c, off);
            }
            if (lane == 0) { redf[wid][r*3+0]=d; redf[wid][r*3+1]=a; redf[wid][r*3+2]=c; }
        }
        __syncthreads();
        if (tid < ROWS_B * 3) {
            float sum = redf[0][tid] + redf[1][tid] + redf[2][tid] + redf[3][tid];
            int r = tid / 3, q = tid % 3;
            int i = i0 + r;
            if (i < F) {
                if      (q == 0) dist2[i] = sum;
                else if (q == 1) rank2[i] = sum;
                else             cnt2[i]  = sum;
            }
        }
    }
}

// ---------------- K2: load hist + eval + partial + last-block final ---------
__global__ __launch_bounds__(TPB) void ape_phase2(
    const float* __restrict__ logits, const float* __restrict__ ious, int F, int EB,
    const int* __restrict__ gCnt, const int* __restrict__ gM1,
    const float* __restrict__ bmaxA,
    const float* __restrict__ dist2, const float* __restrict__ rank2,
    const float* __restrict__ cnt2,
    float* __restrict__ pp, float* __restrict__ pv,
    int* __restrict__ ctr, float* __restrict__ out)
{
    const int tid  = threadIdx.x;
    const int lane = tid & 63, wid = tid >> 6;

    // load global int hist -> float2 LDS (one int4-pair per thread)
    __shared__ float2 h[B_BINS];
    {
        const int b4 = tid * 4;   // B_BINS == 4*TPB
        int4 c4 = *reinterpret_cast<const int4*>(gCnt + b4);
        int4 m4 = *reinterpret_cast<const int4*>(gM1 + b4);
        h[b4 + 0] = make_float2((float)c4.x, (float)m4.x * M1INV);
        h[b4 + 1] = make_float2((float)c4.y, (float)m4.y * M1INV);
        h[b4 + 2] = make_float2((float)c4.z, (float)m4.z * M1INV);
        h[b4 + 3] = make_float2((float)c4.w, (float)m4.w * M1INV);
    }

    const int i0 = (int)blockIdx.x * ROWS_E;
    float fKC[ROWS_E];
#pragma unroll
    for (int r = 0; r < ROWS_E; ++r) {
        int i = i0 + r;
        fKC[r] = (i < F) ? logits[i] * APE_KC : __builtin_inff();
    }
    __syncthreads();

    float rk[ROWS_E], dt[ROWS_E];
#pragma unroll
    for (int r = 0; r < ROWS_E; ++r) { rk[r] = 0.f; dt[r] = 0.f; }

    for (int it = 0; it < B_BINS; it += TPB) {
        const int b = it + tid;
        float2 cm = h[b];
        float cKC  = fmaf((float)b, BIN_DL * APE_KC, (BIN_LO + 0.5f * BIN_DL) * APE_KC);
        float m1x4 = cm.y * APE_LAMB;
        float m1kc = cm.y * APE_KC;
#pragma unroll
        for (int r = 0; r < ROWS_E; ++r) {
            float dl = cKC - fKC[r];
            float dm = (dl > -APE_KC) ? dl : NINF;
            float u  = exp2g(dm);
            float o  = 1.0f + u;
            float rr = rcpg(o);
            float lg = log2g(o);
            float s  = 1.0f - rr;
            rk[r] = fmaf(cm.x, s,  rk[r]);
            rk[r] = fmaf(m1x4, s * rr, rk[r]);
            dt[r] = fmaf(cm.x, lg, dt[r]);
            dt[r] = fmaf(m1kc, s,  dt[r]);
        }
    }

    __shared__ float red[4][ROWS_E * 2];
#pragma unroll
    for (int r = 0; r < ROWS_E; ++r) {
        float a = rk[r], d = dt[r];
        for (int off = 32; off > 0; off >>= 1) {
            a += __shfl_down(a, off);
            d += __shfl_down(d, off);
        }
        if (lane == 0) { red[wid][r*2+0] = a; red[wid][r*2+1] = d; }
    }
    __syncthreads();

    // per-block partial of the final sum, published fence-free
    __shared__ int lastFlag;
    if (tid == 0) {
        float gmax = NINF;
#pragma unroll
        for (int k = 0; k < NB; ++k) gmax = fmaxf(gmax, bmaxA[k]);
        float sper = 0.f, sval = 0.f;
#pragma unroll
        for (int r = 0; r < ROWS_E; ++r) {
            int i = i0 + r;
            if (i < F) {
                float rowRank = red[0][r*2+0] + red[1][r*2+0] + red[2][r*2+0] + red[3][r*2+0];
                float rowDist = red[0][r*2+1] + red[1][r*2+1] + red[2][r*2+1] + red[3][r*2+1];
                float rkv = rowRank + rank2[i];
                float dtv = (rowDist + dist2[i]) * APE_LN2;
                bool valid = (gmax > logits[i] - 1.0f) || (cnt2[i] > 0.f);
                if (valid) {
                    sper += dtv * ious[i] / rkv;
                    sval += 1.f;
                }
            }
        }
        ST_AGENT(&pp[blockIdx.x], sper);   // sc0 sc1: bypass L2, land at LLC
        ST_AGENT(&pv[blockIdx.x], sval);
        asm volatile("s_waitcnt vmcnt(0)" ::: "memory");  // stores complete at LLC
        int old = __hip_atomic_fetch_add(ctr, 1, __ATOMIC_RELAXED,
                                         __HIP_MEMORY_SCOPE_AGENT);
        lastFlag = (old == EB - 1) ? 1 : 0;
    }
    __syncthreads();
    if (!lastFlag) return;

    // last block: deterministic fixed-order reduce of the partials
    float sp = 0.f, sv = 0.f;
    for (int k = tid; k < EB; k += TPB) {
        sp += LD_AGENT(&pp[k]);
        sv += LD_AGENT(&pv[k]);
    }
    __shared__ float rp[4], rv[4];
    for (int off = 32; off > 0; off >>= 1) {
        sp += __shfl_down(sp, off);
        sv += __shfl_down(sv, off);
    }
    if (lane == 0) { rp[wid] = sp; rv[wid] = sv; }
    __syncthreads();
    if (tid == 0) {
        float p = rp[0] + rp[1] + rp[2] + rp[3];
        float v = rv[0] + rv[1] + rv[2] + rv[3];
        out[0] = p / fmaxf(v, 1.f) / APE_LAMB;
    }
}

extern "C" void kernel_launch(void* const* d_in, const int* in_sizes, int n_in,
                              void* d_out, int out_size, void* d_ws, size_t ws_size,
                              hipStream_t stream) {
    const float* logits = (const float*)d_in[0];
    const float* ious   = (const float*)d_in[2];
    const int N = in_sizes[0];
    const int F = in_sizes[2];
    const int M = N - F;

    const int FB = (F + ROWS_B - 1) / ROWS_B;
    const int EB = (F + ROWS_E - 1) / ROWS_E;

    int*   gCnt  = (int*)d_ws;               // [B_BINS]
    int*   gM1   = gCnt + B_BINS;            // [B_BINS]
    int*   ctr   = gM1 + B_BINS;             // [1]   (zeroed with hist)
    float* bmaxA = (float*)(ctr + 1);        // [NB]
    float* dist2 = bmaxA + NB;               // [F]
    float* rank2 = dist2 + F;                // [F]
    float* cnt2  = rank2 + F;                // [F]
    float* pp    = cnt2 + F;                 // [EB]
    float* pv    = pp + EB;                  // [EB]

    int chunkH = ((M + NB - 1) / NB + 3) & ~3;
    if (chunkH < 4) chunkH = 4;

    hipMemsetAsync(gCnt, 0, (2 * B_BINS + 1) * sizeof(int), stream);
    ape_phase1<<<NB + FB, TPB, 0, stream>>>(logits, ious, F, M, chunkH,
                                            gCnt, gM1, bmaxA, dist2, rank2, cnt2);
    ape_phase2<<<EB, TPB, 0, stream>>>(logits, ious, F, EB, gCnt, gM1, bmaxA,
                                       dist2, rank2, cnt2, pp, pv, ctr,
                                       (float*)d_out);
}

// Round 9
// 21.453 us; speedup vs baseline: 1.1335x; 1.1335x over previous
//
#include <hip/hip_runtime.h>
#include <hip/hip_bf16.h>

// APELoss via moment-corrected histogram, 3 dispatches (R7 structure + tiny
// merge kernel). R8 lesson: global device-scope atomic hist accumulation
// serializes at the coherence point (~64K same-address RMWs) -- keep
// per-block segments + fixed-order merge. R6 lesson: in-graph dispatch
// boundaries are ~free; software polling is not.
//
// K1 (NB=16 hist blocks + F/4 fg-fg blocks):
//   - hist blocks: per-warp LDS sub-histograms (4x, cuts same-bin LDS-atomic
//     contention on the normal-dist center) of a bg slice -> per-block float2
//     segment (count, first moment; 2^28 fixed point) + per-block bg max.
//     Block 0 zeroes K2's counter.
//   - fg-fg blocks: exact F x F part (dist2/rank2/cnt2 per row).
// K1.5 (4 blocks): fold the 16 segments into ONE float2 histogram (fixed
//   order -> deterministic); block 0 thread 0 reduces bmaxA -> gmax scalar.
// K2 (EB = F/4 eval blocks): load merged 8KB hist -> LDS, evaluate 4 rows
//   over B_BINS bins with first-order Taylor, fold with fg-fg partials +
//   validity into per-block (sper,sval). Publish agent-scope (sc0 sc1,
//   LLC-direct) stores + s_waitcnt vmcnt(0) + relaxed agent atomicAdd
//   (NO __threadfence -- R4: per-block agent fence = L2 writeback ~15us);
//   block seeing EB-1 reduces partials in fixed order, writes the scalar.
//
// Math (log2 domain): dl = KC*(c - f), mask dl > -KC else -inf.
//   u = 2^dl, o = 1+u, rr = rcp(o): sigmoid = 1-rr, softplus/ln2 = log2(o)
//   d(sigmoid)/dv = LAMB*(1-rr)*rr ; d(softplus/ln2)/dv = KC*(1-rr)
// valid_i = (gmax > f_i - 1) || fg_pos_count_i > 0.

#define APE_LAMB 4.0f
#define APE_KC   5.770780163555856f   // LAMB * log2(e)
#define APE_LN2  0.6931471805599453f
#define NINF     (-__builtin_inff())

__device__ __forceinline__ float exp2g(float x) { return __builtin_amdgcn_exp2f(x); }
__device__ __forceinline__ float log2g(float x) { return __builtin_amdgcn_logf(x); }
__device__ __forceinline__ float rcpg(float x)  { return __builtin_amdgcn_rcpf(x); }

constexpr int   B_BINS  = 1024;
constexpr int   NB      = 16;     // histogram segment blocks
constexpr int   MB      = 4;      // merge blocks (B_BINS / TPB)
constexpr int   TPB     = 256;
constexpr float BIN_LO  = -5.12f;
constexpr float BIN_DL  = 0.01f;
constexpr float BIN_INV = 100.0f;
constexpr float M1SCALE = 268435456.0f;             // 2^28
constexpr float M1INV   = 3.725290298461914e-09f;   // 2^-28
constexpr int   ROWS_E  = 4;      // fg rows per eval block
constexpr int   ROWS_B  = 4;      // fg rows per fg-fg block

#define ST_AGENT(p, v) __hip_atomic_store((p), (v), __ATOMIC_RELAXED, __HIP_MEMORY_SCOPE_AGENT)
#define LD_AGENT(p)    __hip_atomic_load((p), __ATOMIC_RELAXED, __HIP_MEMORY_SCOPE_AGENT)

// ---------------- K1: hist segments + bg max + fg-fg + ctr reset ------------
__global__ __launch_bounds__(TPB) void ape_phase1(
    const float* __restrict__ logits, const float* __restrict__ ious,
    int F, int M, int chunkH,
    float2* __restrict__ gH, float* __restrict__ bmaxA,
    float* __restrict__ dist2, float* __restrict__ rank2, float* __restrict__ cnt2,
    int* __restrict__ ctr)
{
    const int tid  = threadIdx.x;
    const int lane = tid & 63, wid = tid >> 6;

    if (blockIdx.x == 0 && tid == 0) *ctr = 0;   // visible to K2 via kernel boundary

    if ((int)blockIdx.x < NB) {
        // ---- histogram of one bg slice (per-warp sub-hists) ----
        __shared__ int hc[4][B_BINS];
        __shared__ int hm[4][B_BINS];
        for (int b = tid; b < 4 * B_BINS; b += TPB) {
            hc[b >> 10][b & (B_BINS - 1)] = 0;
            hm[b >> 10][b & (B_BINS - 1)] = 0;
        }
        __syncthreads();

        const float* bg = logits + F;
        const int start = (int)blockIdx.x * chunkH;
        const int end   = min(start + chunkH, M);
        float bmax = NINF;

        for (int j = start + tid * 4; j < end; j += TPB * 4) {
            float v[4];
            if (j + 4 <= end) {
                float4 q = *reinterpret_cast<const float4*>(bg + j);
                v[0] = q.x; v[1] = q.y; v[2] = q.z; v[3] = q.w;
            } else {
#pragma unroll
                for (int k = 0; k < 4; ++k) v[k] = (j + k < end) ? bg[j + k] : NINF;
            }
#pragma unroll
            for (int k = 0; k < 4; ++k) {
                if (j + k >= end) continue;
                float x = v[k];
                bmax = fmaxf(bmax, x);
                int b = (int)((x - BIN_LO) * BIN_INV);
                b = min(max(b, 0), B_BINS - 1);
                float c = fmaf((float)b, BIN_DL, BIN_LO + 0.5f * BIN_DL);
                int q = __float2int_rn((x - c) * M1SCALE);
                atomicAdd(&hc[wid][b], 1);
                atomicAdd(&hm[wid][b], q);
            }
        }
        __syncthreads();
        const int base = (int)blockIdx.x * B_BINS;
        for (int b = tid; b < B_BINS; b += TPB) {
            int c = hc[0][b] + hc[1][b] + hc[2][b] + hc[3][b];
            int m = hm[0][b] + hm[1][b] + hm[2][b] + hm[3][b];
            gH[base + b] = make_float2((float)c, (float)m * M1INV);
        }
        __shared__ float rm[4];
        for (int off = 32; off > 0; off >>= 1) bmax = fmaxf(bmax, __shfl_down(bmax, off));
        if (lane == 0) rm[wid] = bmax;
        __syncthreads();
        if (tid == 0)
            bmaxA[blockIdx.x] = fmaxf(fmaxf(rm[0], rm[1]), fmaxf(rm[2], rm[3]));
    } else {
        // ---- fg-fg exact pairwise ----
        const int i0 = ((int)blockIdx.x - NB) * ROWS_B;
        float fgl[ROWS_B], ioui[ROWS_B];
#pragma unroll
        for (int r = 0; r < ROWS_B; ++r) {
            int i = i0 + r;
            fgl[r]  = (i < F) ? logits[i] * APE_KC : __builtin_inff();
            ioui[r] = (i < F) ? ious[i] : 0.f;
        }
        float dist[ROWS_B], rank[ROWS_B], cnt[ROWS_B];
#pragma unroll
        for (int r = 0; r < ROWS_B; ++r) { dist[r]=0.f; rank[r]=0.f; cnt[r]=0.f; }

        for (int j = tid; j < F; j += TPB) {
            float fjl  = logits[j] * APE_KC;
            float iouj = ious[j];
#pragma unroll
            for (int r = 0; r < ROWS_B; ++r) {
                float dl = fjl - fgl[r];
                bool above = dl > -APE_KC;
                float dm = above ? dl : NINF;
                float u  = exp2g(dm);
                float o  = 1.0f + u;
                float sig = 1.0f - rcpg(o);
                float spl = log2g(o);
                bool pos = iouj < ioui[r];
                rank[r] += sig;
                dist[r] += pos ? spl : 0.f;
                cnt[r]  += (above && pos) ? 1.f : 0.f;
            }
        }
        __shared__ float redf[4][ROWS_B * 3];
#pragma unroll
        for (int r = 0; r < ROWS_B; ++r) {
            float d = dist[r], a = rank[r], c = cnt[r];
            for (int off = 32; off > 0; off >>= 1) {
                d += __shfl_down(d, off);
                a += __shfl_down(a, off);
                c += __shfl_down(c, off);
            }
            if (lane == 0) { redf[wid][r*3+0]=d; redf[wid][r*3+1]=a; redf[wid][r*3+2]=c; }
        }
        __syncthreads();
        if (tid < ROWS_B * 3) {
            float sum = redf[0][tid] + redf[1][tid] + redf[2][tid] + redf[3][tid];
            int r = tid / 3, q = tid % 3;
            int i = i0 + r;
            if (i < F) {
                if      (q == 0) dist2[i] = sum;
                else if (q == 1) rank2[i] = sum;
                else             cnt2[i]  = sum;
            }
        }
    }
}

// ---------------- K1.5: fold 16 segments -> one histogram + gmax ------------
__global__ __launch_bounds__(TPB) void ape_merge(
    const float2* __restrict__ gH, const float* __restrict__ bmaxA,
    float2* __restrict__ gHm, float* __restrict__ gmaxOut)
{
    const int b = (int)blockIdx.x * TPB + threadIdx.x;   // MB*TPB == B_BINS
    float c = 0.f, m = 0.f;
#pragma unroll
    for (int s = 0; s < NB; ++s) {
        float2 cm = gH[s * B_BINS + b];
        c += cm.x;
        m += cm.y;
    }
    gHm[b] = make_float2(c, m);
    if (blockIdx.x == 0 && threadIdx.x == 0) {
        float g = NINF;
#pragma unroll
        for (int k = 0; k < NB; ++k) g = fmaxf(g, bmaxA[k]);
        gmaxOut[0] = g;
    }
}

// ---------------- K2: load hist + eval + partial + last-block final ---------
__global__ __launch_bounds__(TPB) void ape_phase2(
    const float* __restrict__ logits, const float* __restrict__ ious, int F, int EB,
    const float2* __restrict__ gHm, const float* __restrict__ gmaxIn,
    const float* __restrict__ dist2, const float* __restrict__ rank2,
    const float* __restrict__ cnt2,
    float* __restrict__ pp, float* __restrict__ pv,
    int* __restrict__ ctr, float* __restrict__ out)
{
    const int tid  = threadIdx.x;
    const int lane = tid & 63, wid = tid >> 6;

    // load merged hist (8KB) -> LDS: 4 bins (= 2 float4) per thread
    __shared__ float2 h[B_BINS];
    {
        const float4* src = reinterpret_cast<const float4*>(gHm);
        float4 a = src[tid * 2 + 0];
        float4 b = src[tid * 2 + 1];
        h[tid * 4 + 0] = make_float2(a.x, a.y);
        h[tid * 4 + 1] = make_float2(a.z, a.w);
        h[tid * 4 + 2] = make_float2(b.x, b.y);
        h[tid * 4 + 3] = make_float2(b.z, b.w);
    }

    const int i0 = (int)blockIdx.x * ROWS_E;
    float fKC[ROWS_E];
#pragma unroll
    for (int r = 0; r < ROWS_E; ++r) {
        int i = i0 + r;
        fKC[r] = (i < F) ? logits[i] * APE_KC : __builtin_inff();
    }
    __syncthreads();

    float rk[ROWS_E], dt[ROWS_E];
#pragma unroll
    for (int r = 0; r < ROWS_E; ++r) { rk[r] = 0.f; dt[r] = 0.f; }

    for (int it = 0; it < B_BINS; it += TPB) {
        const int b = it + tid;
        float2 cm = h[b];
        float cKC  = fmaf((float)b, BIN_DL * APE_KC, (BIN_LO + 0.5f * BIN_DL) * APE_KC);
        float m1x4 = cm.y * APE_LAMB;
        float m1kc = cm.y * APE_KC;
#pragma unroll
        for (int r = 0; r < ROWS_E; ++r) {
            float dl = cKC - fKC[r];
            float dm = (dl > -APE_KC) ? dl : NINF;
            float u  = exp2g(dm);
            float o  = 1.0f + u;
            float rr = rcpg(o);
            float lg = log2g(o);
            float s  = 1.0f - rr;
            rk[r] = fmaf(cm.x, s,  rk[r]);
            rk[r] = fmaf(m1x4, s * rr, rk[r]);
            dt[r] = fmaf(cm.x, lg, dt[r]);
            dt[r] = fmaf(m1kc, s,  dt[r]);
        }
    }

    __shared__ float red[4][ROWS_E * 2];
#pragma unroll
    for (int r = 0; r < ROWS_E; ++r) {
        float a = rk[r], d = dt[r];
        for (int off = 32; off > 0; off >>= 1) {
            a += __shfl_down(a, off);
            d += __shfl_down(d, off);
        }
        if (lane == 0) { red[wid][r*2+0] = a; red[wid][r*2+1] = d; }
    }
    __syncthreads();

    // per-block partial of the final sum, published fence-free
    __shared__ int lastFlag;
    if (tid == 0) {
        const float gmax = gmaxIn[0];
        float sper = 0.f, sval = 0.f;
#pragma unroll
        for (int r = 0; r < ROWS_E; ++r) {
            int i = i0 + r;
            if (i < F) {
                float rowRank = red[0][r*2+0] + red[1][r*2+0] + red[2][r*2+0] + red[3][r*2+0];
                float rowDist = red[0][r*2+1] + red[1][r*2+1] + red[2][r*2+1] + red[3][r*2+1];
                float rkv = rowRank + rank2[i];
                float dtv = (rowDist + dist2[i]) * APE_LN2;
                bool valid = (gmax > logits[i] - 1.0f) || (cnt2[i] > 0.f);
                if (valid) {
                    sper += dtv * ious[i] / rkv;
                    sval += 1.f;
                }
            }
        }
        ST_AGENT(&pp[blockIdx.x], sper);   // sc0 sc1: bypass L2, land at LLC
        ST_AGENT(&pv[blockIdx.x], sval);
        asm volatile("s_waitcnt vmcnt(0)" ::: "memory");  // stores complete at LLC
        int old = __hip_atomic_fetch_add(ctr, 1, __ATOMIC_RELAXED,
                                         __HIP_MEMORY_SCOPE_AGENT);
        lastFlag = (old == EB - 1) ? 1 : 0;
    }
    __syncthreads();
    if (!lastFlag) return;

    // last block: deterministic fixed-order reduce of the partials
    float sp = 0.f, sv = 0.f;
    for (int k = tid; k < EB; k += TPB) {
        sp += LD_AGENT(&pp[k]);
        sv += LD_AGENT(&pv[k]);
    }
    __shared__ float rp[4], rv[4];
    for (int off = 32; off > 0; off >>= 1) {
        sp += __shfl_down(sp, off);
        sv += __shfl_down(sv, off);
    }
    if (lane == 0) { rp[wid] = sp; rv[wid] = sv; }
    __syncthreads();
    if (tid == 0) {
        float p = rp[0] + rp[1] + rp[2] + rp[3];
        float v = rv[0] + rv[1] + rv[2] + rv[3];
        out[0] = p / fmaxf(v, 1.f) / APE_LAMB;
    }
}

extern "C" void kernel_launch(void* const* d_in, const int* in_sizes, int n_in,
                              void* d_out, int out_size, void* d_ws, size_t ws_size,
                              hipStream_t stream) {
    const float* logits = (const float*)d_in[0];
    const float* ious   = (const float*)d_in[2];
    const int N = in_sizes[0];
    const int F = in_sizes[2];
    const int M = N - F;

    const int FB = (F + ROWS_B - 1) / ROWS_B;
    const int EB = (F + ROWS_E - 1) / ROWS_E;

    float2* gH   = (float2*)d_ws;              // [NB][B_BINS]
    float2* gHm  = gH + NB * B_BINS;           // [B_BINS]
    float*  bmaxA = (float*)(gHm + B_BINS);    // [NB]
    float*  gmax  = bmaxA + NB;                // [1]
    float*  dist2 = gmax + 1;                  // [F]
    float*  rank2 = dist2 + F;                 // [F]
    float*  cnt2  = rank2 + F;                 // [F]
    float*  pp    = cnt2 + F;                  // [EB]
    float*  pv    = pp + EB;                   // [EB]
    int*    ctr   = (int*)(pv + EB);           // [1]

    int chunkH = ((M + NB - 1) / NB + 3) & ~3;
    if (chunkH < 4) chunkH = 4;

    ape_phase1<<<NB + FB, TPB, 0, stream>>>(logits, ious, F, M, chunkH,
                                            gH, bmaxA, dist2, rank2, cnt2, ctr);
    ape_merge<<<MB, TPB, 0, stream>>>(gH, bmaxA, gHm, gmax);
    ape_phase2<<<EB, TPB, 0, stream>>>(logits, ious, F, EB, gHm, gmax,
                                       dist2, rank2, cnt2, pp, pv, ctr,
                                       (float*)d_out);
}